// Round 15
// baseline (118.193 us; speedup 1.0000x reference)
//
#include <hip/hip_runtime.h>

// BackgroundNoiseLayer, round 15: r14 + wave-private LDS store transpose.
//   out[t, n*5+r] = sum_k spikes[t,k] * W[k, n*5+r],
//   W[k, c] = scatter-add over edges e (cols[e]=k, rows[e]=n) of weights[e]*tau[e,r]
//
// Store-pattern theory: all prior rounds issued store instrs scattering
// 16 t-rows x 64 B (t on the lane axis) -> ~3 TB/s. Staging each m-pair's
// 16x128 B tile through wave-private LDS and copying linearly makes each
// store instr cover 8 rows x full 128 B lines.
//
// memset: zero counters [part][bin]
// K1 : bucket edges, 4/thread; 16 B records into XCD-local partitions;
//      builds fragment-ordered bf16 spike table spbf.
// K2 : preload records -> zero f32 slice [128][80] -> LDS atomic scatter ->
//      convert reads -> (bs preload in flight across LBAR) -> swizzled bf16
//      ds_writes -> barrier -> GEMM per m-pair -> stage pair tile in private
//      LDS (stride 144) -> linear copy stores (8 rows x 128 B per instr).

#define N_NEURONS 50000
#define N_BKG     100
#define N_SYN     5
#define N_EDGES   500000
#define SEQ_T     250
#define NCOL      (N_NEURONS * N_SYN)   // 250000
#define RPB       16                    // neurons per bin
#define NBINS     (N_NEURONS / RPB)     // 3125
#define NPART     8                     // record partitions (one per XCD)
#define CAP_P     64                    // records per (bin, part)
#define RECS_BIN  (NPART * CAP_P)       // 512 records / bin
#define CPADF     80                    // f32 slice leading dim
#define BCOLS     80                    // output cols per bin
#define STRIDE_J  37                    // coprime to 390 and 391

#define LDS_BYTES 40960                 // slice 128*80*4; frags [0,20480);
                                        // staging [20480, 20480+4*2304)
#define STG_OFF   20480
#define STG_WV    2304                  // 16 rows * 144 B (128 data + 16 pad)

// d_ws layout
#define WS_COUNT_OFF 0                  // NPART*NBINS u32 = 100 KB
#define WS_SPB_OFF   131072             // 4096 * 16 B spike frags
#define WS_REC_OFF   262144             // NBINS*512*16 B = 25.6 MB

typedef __attribute__((ext_vector_type(8))) short bf16x8;
typedef __attribute__((ext_vector_type(4))) float f32x4;

// lgkm-only barrier (convert read->write boundary; bs loads stay in flight)
#define LBAR() asm volatile("s_waitcnt lgkmcnt(0)\n\ts_barrier" ::: "memory")

__device__ inline unsigned short bf16_rne(float f) {
    unsigned u = __builtin_bit_cast(unsigned, f);
    u += 0x7FFFu + ((u >> 16) & 1u);
    return (unsigned short)(u >> 16);
}
__device__ inline float bf16_up(unsigned hw) {
    return __builtin_bit_cast(float, hw << 16);
}

// K1: 4 edges/thread; gids < 4096 also build the fragment-ordered spike
// table: unit gid = (nt*4 + kk)*64 + lane, value[i] = bf16(spikes[t, k0+i]),
// t = nt*16+(lane&15), k0 = kk*32+(lane>>4)*8 (zero-padded).
__global__ __launch_bounds__(256) void bucket_kernel(
        const float* __restrict__ weights,
        const float* __restrict__ tau,
        const int*   __restrict__ rows,
        const int*   __restrict__ cols,
        const float* __restrict__ spikes,
        unsigned* __restrict__ count,
        uint4* __restrict__ rec,
        bf16x8* __restrict__ spbf) {
    int gid = blockIdx.x * 256 + threadIdx.x;
    if (gid < 4096) {
        int lane = gid & 63;
        int kk   = (gid >> 6) & 3;
        int nt   = gid >> 8;
        int t    = nt * 16 + (lane & 15);
        int k0   = kk * 32 + (lane >> 4) * 8;
        bf16x8 v;
#pragma unroll
        for (int i = 0; i < 8; ++i) {
            float s = 0.f;
            if (t < SEQ_T && (k0 + i) < N_BKG)
                s = spikes[t * N_BKG + k0 + i];      // 0/1 -> bf16 exact
            v[i] = (short)bf16_rne(s);
        }
        spbf[gid] = v;
    }
    int part = blockIdx.x & (NPART - 1);         // XCD-local partition
#pragma unroll
    for (int u = 0; u < 4; ++u) {
        int e = gid * 4 + u;                     // four independent chains
        if (e >= N_EDGES) continue;
        int row = rows[e];
        int col = cols[e];
        float w = weights[e];
        const float* tp = tau + (size_t)e * N_SYN;
        int bin = row >> 4;
        unsigned slot = atomicAdd(&count[part * NBINS + bin], 1u);
        if (slot >= CAP_P) continue;             // statistically impossible
        uint4 r;
        r.x = ((unsigned)col << 4) | (unsigned)(row & 15);
        r.y = (unsigned)bf16_rne(w * tp[0]) | ((unsigned)bf16_rne(w * tp[1]) << 16);
        r.z = (unsigned)bf16_rne(w * tp[2]) | ((unsigned)bf16_rne(w * tp[3]) << 16);
        r.w = (unsigned)bf16_rne(w * tp[4]);
        rec[(size_t)bin * RECS_BIN + part * CAP_P + slot] = r;
    }
}

// K2: fused scatter + convert + MFMA GEMM + transposed stores.
// 3125 blocks x 256 (4 waves). Swapped operands: A = W bf16 (M = c),
// B = spike frag (N = t), k = (l>>4)*8+i. D: col = t = l&15,
// row = c = (l>>4)*4+reg (mapping verified rounds 5-14).
__global__ __launch_bounds__(256, 4) void fused_kernel(
        const unsigned* __restrict__ count,
        const uint4* __restrict__ rec,
        const bf16x8* __restrict__ spbf,
        float* __restrict__ out) {
    __shared__ __align__(16) char lds[LDS_BYTES];
    float* slice = (float*)lds;                  // f32 [128][80], rows >=100 stay 0

    const int tid = threadIdx.x;
    const int l   = tid & 63;
    const int wv  = tid >> 6;
    const int lc  = l & 15;
    const int lq  = l >> 4;

    // XCD chunking + strided traversal within the chunk (bijective overall)
    const int orig = blockIdx.x;
    const int xcd  = orig & 7;
    const int j    = orig >> 3;
    const int qx   = (xcd < 5) ? 391 : 390;      // 3125 = 5*391 + 3*390
    const int base = (xcd < 5) ? xcd * 391 : 5 * 391 + (xcd - 5) * 390;
    const int bin  = base + (j * STRIDE_J) % qx;

    // ---- preload records: wave wv owns partitions wv and wv+4 ----
    const uint4* rbin = rec + (size_t)bin * RECS_BIN;
    unsigned cntA = count[wv * NBINS + bin];
    unsigned cntB = count[(4 + wv) * NBINS + bin];
    if (cntA > CAP_P) cntA = CAP_P;
    if (cntB > CAP_P) cntB = CAP_P;
    uint4 ra = rbin[wv * CAP_P + l];             // unguarded: region allocated
    uint4 rb = rbin[(4 + wv) * CAP_P + l];
    bool havea = (unsigned)l < cntA;
    bool haveb = (unsigned)l < cntB;

    // ---- zero f32 slice: 128*80 f32 = 2560 f32x4 (incl. pad rows) ----
    {
        f32x4* s4 = (f32x4*)lds;
        f32x4 z = (f32x4){0.f, 0.f, 0.f, 0.f};
#pragma unroll
        for (int jj = 0; jj < 10; ++jj)
            s4[tid + jj * 256] = z;
    }
    __syncthreads();

    // ---- LDS f32 atomic scatter ----
    if (havea) {
        float* bp = &slice[(ra.x >> 4) * CPADF + (ra.x & 15u) * N_SYN];
        atomicAdd(bp + 0, bf16_up(ra.y & 0xFFFFu));
        atomicAdd(bp + 1, bf16_up(ra.y >> 16));
        atomicAdd(bp + 2, bf16_up(ra.z & 0xFFFFu));
        atomicAdd(bp + 3, bf16_up(ra.z >> 16));
        atomicAdd(bp + 4, bf16_up(ra.w & 0xFFFFu));
    }
    if (haveb) {
        float* bp = &slice[(rb.x >> 4) * CPADF + (rb.x & 15u) * N_SYN];
        atomicAdd(bp + 0, bf16_up(rb.y & 0xFFFFu));
        atomicAdd(bp + 1, bf16_up(rb.y >> 16));
        atomicAdd(bp + 2, bf16_up(rb.z & 0xFFFFu));
        atomicAdd(bp + 3, bf16_up(rb.z >> 16));
        atomicAdd(bp + 4, bf16_up(rb.w & 0xFFFFu));
    }
    __syncthreads();

    // ---- convert reads: slice -> registers (unguarded; pad rows are 0) ----
    bf16x8 hi[5];
#pragma unroll
    for (int jj = 0; jj < 5; ++jj) {
        int m  = tid + jj * 256;                 // 0..1279
        int c  = m % BCOLS;
        int kb = m / BCOLS;                      // 0..15
#pragma unroll
        for (int i = 0; i < 8; ++i)
            hi[jj][i] = (short)bf16_rne(slice[(kb * 8 + i) * CPADF + c]);
    }

    // ---- issue spike-fragment preload NOW; in flight across LBAR ----
    bf16x8 bs[4][4];
#pragma unroll
    for (int n = 0; n < 4; ++n)
#pragma unroll
        for (int kk = 0; kk < 4; ++kk)
            bs[n][kk] = spbf[((wv * 4 + n) * 4 + kk) * 64 + l];

    LBAR();                                      // convert reads done

    // ---- convert writes: transposed [c][k], XOR-swizzled, [0,20480) ----
#pragma unroll
    for (int jj = 0; jj < 5; ++jj) {
        int m  = tid + jj * 256;
        int c  = m % BCOLS;
        int kb = m / BCOLS;
        unsigned bo = (unsigned)(((c << 8) + (kb << 4)) ^ ((c & 7) << 4));
        *(bf16x8*)(lds + bo) = hi[jj];
    }
    __syncthreads();                             // drains lgkm + vmcnt (bs ready)

    // ---- GEMM per m-pair + transposed stores via wave-private staging ----
    const size_t cb = (size_t)bin * BCOLS;
    char* stg = lds + STG_OFF + wv * STG_WV;     // 16 rows x 144 B, dead slice区

#pragma unroll
    for (int mp = 0; mp < 2; ++mp) {             // full pairs {0,1},{2,3}
        f32x4 acc[2][4];
#pragma unroll
        for (int mi = 0; mi < 2; ++mi)
#pragma unroll
            for (int n = 0; n < 4; ++n)
                acc[mi][n] = (f32x4){0.f, 0.f, 0.f, 0.f};

#pragma unroll
        for (int mi = 0; mi < 2; ++mi) {
            int c = (mp * 2 + mi) * 16 + lc;
#pragma unroll
            for (int kk = 0; kk < 4; ++kk) {
                int bor = (((c << 8) + (kk << 6) + (lq << 4)) ^ ((c & 7) << 4));
                bf16x8 ah = *(const bf16x8*)(lds + bor);
#pragma unroll
                for (int n = 0; n < 4; ++n)
                    acc[mi][n] = __builtin_amdgcn_mfma_f32_16x16x32_bf16(
                                     ah, bs[n][kk], acc[mi][n], 0, 0, 0);
            }
        }
        // per n-tile: stage 16 rows x 128 B, then copy out linearly
        // (8 rows x full 128 B lines per store instruction)
#pragma unroll
        for (int n = 0; n < 4; ++n) {
            *(f32x4*)(stg + lc * 144 + lq * 16)      = acc[0][n];
            *(f32x4*)(stg + lc * 144 + 64 + lq * 16) = acc[1][n];
            // compiler inserts lgkmcnt before dependent reads (same wave)
            const int tb = (wv * 4 + n) * 16;
            const size_t cpb = cb + mp * 32;     // pair's 32-col window
#pragma unroll
            for (int p = 0; p < 3; ++p) {
                int off = p * 1024 + l * 16;
                if (off < 16 * 144) {
                    int row = off / 144;
                    int rem = off - row * 144;
                    int t   = tb + row;
                    if (rem < 128 && t < SEQ_T) {
                        f32x4 v = *(const f32x4*)(stg + off);
                        *(f32x4*)(out + (size_t)t * NCOL + cpb + (rem >> 2)) = v;
                    }
                }
            }
        }
    }

    // ---- singleton m=4: direct stores (1/5 of traffic) ----
    {
        f32x4 acc4[4];
#pragma unroll
        for (int n = 0; n < 4; ++n)
            acc4[n] = (f32x4){0.f, 0.f, 0.f, 0.f};
        int c = 4 * 16 + lc;
#pragma unroll
        for (int kk = 0; kk < 4; ++kk) {
            int bor = (((c << 8) + (kk << 6) + (lq << 4)) ^ ((c & 7) << 4));
            bf16x8 ah = *(const bf16x8*)(lds + bor);
#pragma unroll
            for (int n = 0; n < 4; ++n)
                acc4[n] = __builtin_amdgcn_mfma_f32_16x16x32_bf16(
                              ah, bs[n][kk], acc4[n], 0, 0, 0);
        }
#pragma unroll
        for (int n = 0; n < 4; ++n) {
            int t = (wv * 4 + n) * 16 + lc;
            if (t < SEQ_T)
                *(f32x4*)(out + (size_t)t * NCOL + cb + 64 + lq * 4) = acc4[n];
        }
    }
}

extern "C" void kernel_launch(void* const* d_in, const int* in_sizes, int n_in,
                              void* d_out, int out_size, void* d_ws, size_t ws_size,
                              hipStream_t stream) {
    const float* weights = (const float*)d_in[0];
    const float* tau     = (const float*)d_in[1];
    const float* spikes  = (const float*)d_in[2];
    const int*   rows    = (const int*)d_in[3];
    const int*   cols    = (const int*)d_in[4];
    float* out = (float*)d_out;

    char* ws = (char*)d_ws;
    unsigned* count = (unsigned*)(ws + WS_COUNT_OFF);
    bf16x8*   spbf  = (bf16x8*)(ws + WS_SPB_OFF);
    uint4*    rec   = (uint4*)(ws + WS_REC_OFF);

    hipMemsetAsync(count, 0, NPART * NBINS * sizeof(unsigned), stream);

    int eblocks = (N_EDGES / 4 + 255) / 256;     // 489 (4 edges/thread)
    bucket_kernel<<<eblocks, 256, 0, stream>>>(weights, tau, rows, cols, spikes,
                                               count, rec, spbf);

    fused_kernel<<<NBINS, 256, 0, stream>>>(count, rec, spbf, out);
}